// Round 9
// baseline (198.128 us; speedup 1.0000x reference)
//
#include <hip/hip_runtime.h>
#include <hip/hip_bf16.h>
#include <cstdint>

#define BATCH 4096
#define LAT   2048
#define NFREQ 2074
#define KPAD  2112   // NFREQ padded up to a multiple of 64 (zero-filled); 66 K-iters

typedef __bf16 bf16x8 __attribute__((ext_vector_type(8)));
typedef float  f32x4  __attribute__((ext_vector_type(4)));

__device__ __forceinline__ unsigned short f2bf(float f) {
    unsigned int u = __float_as_uint(f);
    u = (u + 0x7fffu + ((u >> 16) & 1u)) >> 16;
    return (unsigned short)u;
}

__device__ __forceinline__ void gload_lds16(const unsigned short* g, unsigned short* l) {
    __builtin_amdgcn_global_load_lds(
        (const __attribute__((address_space(1))) unsigned int*)g,
        (__attribute__((address_space(3))) unsigned int*)l,
        16, 0, 0);
}

// ---------------------------------------------------------------------------
// Ledger:
//  - r0-r6: gemm2 K-loop plateau 50-57us across all schedule variants (r0 8w
//    1-barrier best; r2 64x64 neutral; r3 depth-2 vmcnt neutral; r6 thin
//    2-phase worse). 2-phase structural floor confirmed 4 ways.
//  - r5: software grid barrier = +80us. OFF LIMITS (r1: coop launch too).
//  - r8: gemm1 128x128/8-wave + x-cast overlap: 206.7 -> 191.6 (-15). BEST.
//  - r8 analysis: gemm2 FETCH 68MB = cross-XCD replication floor (2*sqrt(8AB)
//    ~ 64MB) -> T1 XCD swizzle would gain ~0. Don't try it.
//  - r9 (this): (1) gemm2 1024-thr / 16 waves of 32x32 / 2 blocks/CU = 32
//    waves/CU (only untried TLP doubling; r3: 16->8w cost 5%); (2) gemm2
//    writes bf16 UNSCALED (halves C-write bytes; error +2^-9 rel, ~0.008
//    total < 0.02 threshold); scale converts bf16->scaled fp32; (3)
//    nontemporal C stores (keep operand panels in L2).
//  - Swizzle (verified r2/r3: conflicts 6.29M -> 0): logical 16B chunk c of
//    row r at physical c ^ ((r>>1)&3), both-sides. Row-base terms must be
//    multiples of 16 (they are: wave/mi/ni offsets).

// prep: 2112 transpose blocks (x-cast lives in gemm1's dispatch).
__global__ void prep_kernel(const float* __restrict__ W,
                            const float* __restrict__ cb,
                            unsigned short* __restrict__ WT,
                            unsigned short* __restrict__ cosT,
                            float* __restrict__ maxp) {
    __shared__ float t[64][65];
    const int bid = blockIdx.x;
    const int tid = threadIdx.x;
    if (bid == 0 && tid == 0) *maxp = -__builtin_inff();
    const float* in     = (bid < 1056) ? W  : cb;
    unsigned short* out = (bid < 1056) ? WT : cosT;
    int b2 = (bid < 1056) ? bid : bid - 1056;
    const int c0 = (b2 % 32) * 64;
    const int r0 = (b2 / 32) * 64;
    for (int i = tid; i < 1024; i += 256) {
        int rr = i >> 4;            // 0..63
        int c4 = (i & 15) * 4;      // 0..60
        int r  = r0 + rr;
        float4 v;
        if (r < NFREQ) v = *(const float4*)&in[(size_t)r * LAT + c0 + c4];
        else           v = make_float4(0.f, 0.f, 0.f, 0.f);
        t[rr][c4 + 0] = v.x; t[rr][c4 + 1] = v.y;
        t[rr][c4 + 2] = v.z; t[rr][c4 + 3] = v.w;
    }
    __syncthreads();
    for (int i = tid; i < 1024; i += 256) {
        int cc = i >> 4;            // 0..63: out row
        int r4 = (i & 15) * 4;      // 0..60: out col group
        ushort4 o;
        o.x = f2bf(t[r4 + 0][cc]); o.y = f2bf(t[r4 + 1][cc]);
        o.z = f2bf(t[r4 + 2][cc]); o.w = f2bf(t[r4 + 3][cc]);
        *(ushort4*)&out[(size_t)(c0 + cc) * KPAD + r0 + r4] = o;
    }
}

// ---------------------------------------------------------------------------
// GEMM1 (unchanged r8 winner): 128x128, 512 thr = 8 waves of 64x32, 3-stage,
// vmcnt(2) straddle, swizzle. Grid dim3(16, 16+16): y>=16 = x-cast blocks.
// C1 stores nontemporal (r9).
template <int N, int K>
__global__ __launch_bounds__(512, 4)
void gemm1_kernel(const unsigned short* __restrict__ A,
                  const unsigned short* __restrict__ Bt,
                  unsigned short* __restrict__ C,
                  const float* __restrict__ x,
                  unsigned short* __restrict__ xb) {
    if (blockIdx.y >= 16) {
        const int cb  = (blockIdx.y - 16) * 16 + blockIdx.x;   // 0..255
        const int tid = threadIdx.x;
        const float4* x4 = (const float4*)x;
        uint4* o4 = (uint4*)xb;
        int i = cb * 512 + tid;                                 // uint4 index
#pragma unroll
        for (int it = 0; it < 8; ++it, i += 131072) {
            float4 a = x4[2 * i];
            float4 b = x4[2 * i + 1];
            union { unsigned short us[8]; uint4 v; } p;
            p.us[0] = f2bf(a.x); p.us[1] = f2bf(a.y); p.us[2] = f2bf(a.z); p.us[3] = f2bf(a.w);
            p.us[4] = f2bf(b.x); p.us[5] = f2bf(b.y); p.us[6] = f2bf(b.z); p.us[7] = f2bf(b.w);
            o4[i] = p.v;
        }
        return;
    }

    __shared__ alignas(16) unsigned short As[3][128 * 32];
    __shared__ alignas(16) unsigned short Bs[3][128 * 32];

    const int tid  = threadIdx.x;
    const int wave = tid >> 6;          // 0..7
    const int lane = tid & 63;
    const int wm   = (wave >> 2) * 64;  // m-half
    const int wn   = (wave & 3) * 32;   // n-quarter
    const int quad = lane >> 4;
    const int l16  = lane & 15;

    const int mBase = blockIdx.y * 128;
    const int nBase = blockIdx.x * 128;

    const int srow = lane >> 2;
    const int sk   = (((lane & 3) ^ ((srow >> 1) & 3))) * 8; // swizzled source

    const unsigned short* Ab1 = A  + (size_t)(mBase + wave * 16 + srow) * K + sk;
    const unsigned short* Bb1 = Bt + (size_t)(nBase + wave * 16 + srow) * K + sk;
    const int coff = (wave * 16) * 32;

    const int pc = (quad ^ ((l16 >> 1) & 3)) * 8;            // swizzled frag read

    constexpr int NIT = K / 32;
    gload_lds16(Ab1, &As[0][coff]);
    gload_lds16(Bb1, &Bs[0][coff]);

    f32x4 acc[4][2] = {};
    int bc = 0;
    for (int j = 0; j < NIT; ++j) {
        const int bn = (bc == 2) ? 0 : bc + 1;
        if (j + 1 < NIT) {
            const int k0 = (j + 1) * 32;
            gload_lds16(Ab1 + k0, &As[bn][coff]);
            gload_lds16(Bb1 + k0, &Bs[bn][coff]);
            asm volatile("s_waitcnt vmcnt(2)\n\ts_barrier" ::: "memory");
        } else {
            asm volatile("s_waitcnt vmcnt(0)\n\ts_barrier" ::: "memory");
        }
        bf16x8 af[4], bfr[2];
#pragma unroll
        for (int mi = 0; mi < 4; ++mi)
            af[mi] = *(const bf16x8*)&As[bc][(wm + mi * 16 + l16) * 32 + pc];
#pragma unroll
        for (int ni = 0; ni < 2; ++ni)
            bfr[ni] = *(const bf16x8*)&Bs[bc][(wn + ni * 16 + l16) * 32 + pc];
#pragma unroll
        for (int mi = 0; mi < 4; ++mi)
#pragma unroll
            for (int ni = 0; ni < 2; ++ni)
                acc[mi][ni] = __builtin_amdgcn_mfma_f32_16x16x32_bf16(
                    af[mi], bfr[ni], acc[mi][ni], 0, 0, 0);
        bc = bn;
    }

    // C/D layout: col = lane&15, row = quad*4 + reg
#pragma unroll
    for (int mi = 0; mi < 4; ++mi)
#pragma unroll
        for (int ni = 0; ni < 2; ++ni) {
            int col = nBase + wn + ni * 16 + l16;
#pragma unroll
            for (int r = 0; r < 4; ++r) {
                int row = mBase + wm + mi * 16 + quad * 4 + r;
                __builtin_nontemporal_store(f2bf(acc[mi][ni][r]),
                                            &C[(size_t)row * N + col]);
            }
        }
}

// ---------------------------------------------------------------------------
// GEMM2 (r9): 128x128 block tile, 1024 thr = 16 waves of 32x32 wave tiles
// (4m x 4n), acc[2][2], 2 blocks/CU -> 32 waves/CU (max TLP). 3-stage LDS,
// 1 DMA/wave/iter (16 chunks / 16 waves), vmcnt(1) straddle, swizzle.
// Writes bf16 UNSCALED + fused global max; scale converts to scaled fp32.
template <int N, int K>
__global__ __launch_bounds__(1024, 8)
void gemm2_kernel(const unsigned short* __restrict__ A,
                  const unsigned short* __restrict__ Bt,
                  unsigned short* __restrict__ Cb,
                  float* __restrict__ maxp) {
    __shared__ alignas(16) unsigned short As[3][128 * 32];
    __shared__ alignas(16) unsigned short Bs[3][128 * 32];
    __shared__ float redbuf[16];

    const int tid  = threadIdx.x;
    const int wave = tid >> 6;          // 0..15
    const int lane = tid & 63;
    const int wm   = (wave >> 2) * 32;  // m-quarter
    const int wn   = (wave & 3) * 32;   // n-quarter
    const int quad = lane >> 4;
    const int l16  = lane & 15;

    const int mBase = blockIdx.y * 128;
    const int nBase = blockIdx.x * 128;

    const int srow = lane >> 2;
    const int sk   = (((lane & 3) ^ ((srow >> 1) & 3))) * 8; // swizzled source

    // staging: waves 0-7 stage A-chunk (rows wave*16..), waves 8-15 B-chunk
    const int schunk = (wave & 7) * 16;
    const unsigned short* Gb = (wave < 8)
        ? A  + (size_t)(mBase + schunk + srow) * K + sk
        : Bt + (size_t)(nBase + schunk + srow) * K + sk;
    unsigned short* Lb0 = (wave < 8) ? &As[0][schunk * 32] : &Bs[0][schunk * 32];
    unsigned short* Lb1 = (wave < 8) ? &As[1][schunk * 32] : &Bs[1][schunk * 32];
    unsigned short* Lb2 = (wave < 8) ? &As[2][schunk * 32] : &Bs[2][schunk * 32];
    unsigned short* Lbs[3] = {Lb0, Lb1, Lb2};

    const int pc = (quad ^ ((l16 >> 1) & 3)) * 8;            // swizzled frag read

    constexpr int NIT = K / 32;
    gload_lds16(Gb, Lbs[0]);

    f32x4 acc[2][2] = {};
    int bc = 0;
    for (int j = 0; j < NIT; ++j) {
        const int bn = (bc == 2) ? 0 : bc + 1;
        if (j + 1 < NIT) {
            gload_lds16(Gb + (j + 1) * 32, Lbs[bn]);
            asm volatile("s_waitcnt vmcnt(1)\n\ts_barrier" ::: "memory");
        } else {
            asm volatile("s_waitcnt vmcnt(0)\n\ts_barrier" ::: "memory");
        }
        bf16x8 af[2], bfr[2];
#pragma unroll
        for (int mi = 0; mi < 2; ++mi)
            af[mi] = *(const bf16x8*)&As[bc][(wm + mi * 16 + l16) * 32 + pc];
#pragma unroll
        for (int ni = 0; ni < 2; ++ni)
            bfr[ni] = *(const bf16x8*)&Bs[bc][(wn + ni * 16 + l16) * 32 + pc];
#pragma unroll
        for (int mi = 0; mi < 2; ++mi)
#pragma unroll
            for (int ni = 0; ni < 2; ++ni)
                acc[mi][ni] = __builtin_amdgcn_mfma_f32_16x16x32_bf16(
                    af[mi], bfr[ni], acc[mi][ni], 0, 0, 0);
        bc = bn;
    }

    // epilogue: bf16 unscaled store (nontemporal) + block max + one atomic
    float vmax = -__builtin_inff();
#pragma unroll
    for (int mi = 0; mi < 2; ++mi)
#pragma unroll
        for (int ni = 0; ni < 2; ++ni) {
            int col = nBase + wn + ni * 16 + l16;
#pragma unroll
            for (int r = 0; r < 4; ++r) {
                int row = mBase + wm + mi * 16 + quad * 4 + r;
                float v = acc[mi][ni][r];
                __builtin_nontemporal_store(f2bf(v), &Cb[(size_t)row * N + col]);
                vmax = fmaxf(vmax, v);
            }
        }
#pragma unroll
    for (int off = 32; off > 0; off >>= 1)
        vmax = fmaxf(vmax, __shfl_xor(vmax, off));
    if (lane == 0) redbuf[wave] = vmax;
    __syncthreads();
    if (tid == 0) {
        float m = redbuf[0];
#pragma unroll
        for (int w = 1; w < 16; ++w) m = fmaxf(m, redbuf[w]);
        if (m >= 0.0f) atomicMax((int*)maxp, __float_as_int(m));
        else           atomicMin((unsigned int*)maxp, __float_as_uint(m));
    }
}

// ---------------------------------------------------------------------------
// scale: bf16 unscaled -> scaled fp32. 8 bf16 in (16B), 8 fp32 out (32B) per
// thread. Traffic 16.5 + 33 MB (was 33 + 33).
__global__ void scale_kernel(const unsigned short* __restrict__ cb,
                             float* __restrict__ out,
                             const float* __restrict__ maxp) {
    int i = blockIdx.x * blockDim.x + threadIdx.x;
    float inv = 1.0f / (*maxp);
    union { uint4 v; unsigned short us[8]; } p;
    p.v = ((const uint4*)cb)[i];
    float4 o0, o1;
    o0.x = __uint_as_float((unsigned int)p.us[0] << 16) * inv;
    o0.y = __uint_as_float((unsigned int)p.us[1] << 16) * inv;
    o0.z = __uint_as_float((unsigned int)p.us[2] << 16) * inv;
    o0.w = __uint_as_float((unsigned int)p.us[3] << 16) * inv;
    o1.x = __uint_as_float((unsigned int)p.us[4] << 16) * inv;
    o1.y = __uint_as_float((unsigned int)p.us[5] << 16) * inv;
    o1.z = __uint_as_float((unsigned int)p.us[6] << 16) * inv;
    o1.w = __uint_as_float((unsigned int)p.us[7] << 16) * inv;
    ((float4*)out)[2 * i]     = o0;
    ((float4*)out)[2 * i + 1] = o1;
}

// ---------------------------------------------------------------------------
extern "C" void kernel_launch(void* const* d_in, const int* in_sizes, int n_in,
                              void* d_out, int out_size, void* d_ws, size_t ws_size,
                              hipStream_t stream) {
    const float* x  = (const float*)d_in[0];  // (4096, 2048)
    const float* W  = (const float*)d_in[1];  // (2074, 2048)
    const float* cb = (const float*)d_in[2];  // (2074, 2048)

    char* ws = (char*)d_ws;
    unsigned short* xb   = (unsigned short*)ws;                                   // [4096][2048] bf16
    unsigned short* WT   = (unsigned short*)(ws + (size_t)BATCH * LAT * 2);       // [2048][2112] bf16
    unsigned short* cosT = (unsigned short*)((char*)WT + (size_t)LAT * KPAD * 2);
    unsigned short* C1   = (unsigned short*)((char*)cosT + (size_t)LAT * KPAD * 2); // [2048][2048] bf16
    unsigned short* C2b  = (unsigned short*)((char*)C1 + (size_t)LAT * LAT * 2);  // [4096][2048] bf16
    float*          maxp = (float*)((char*)C2b + (size_t)BATCH * LAT * 2);
    float*          out  = (float*)d_out;

    // 1. prep: transpose+cast W and cos_basis (+init max)
    prep_kernel<<<2 * 1056, 256, 0, stream>>>(W, cb, WT, cosT, maxp);

    // 2. C1 = cosT x WT^T (128x128 tiles, 256 GEMM blocks) + 256 x-cast blocks
    gemm1_kernel<LAT, KPAD>
        <<<dim3(16, 32), 512, 0, stream>>>(cosT, WT, C1, x, xb);

    // 3. C2b[b][l2] = bf16( sum_l1 xb[b][l1] * C1[l2][l1] ) + global max
    //    (1024 thr, 16 waves of 32x32, 32 waves/CU)
    gemm2_kernel<LAT, LAT>
        <<<dim3(LAT / 128, BATCH / 128), 1024, 0, stream>>>(xb, C1, C2b, maxp);

    // 4. out = fp32(C2b) / max
    scale_kernel<<<(out_size / 8) / 256, 256, 0, stream>>>(C2b, out, maxp);
}

// Round 10
// 181.742 us; speedup vs baseline: 1.0902x; 1.0902x over previous
//
#include <hip/hip_runtime.h>
#include <hip/hip_bf16.h>
#include <cstdint>

#define BATCH 4096
#define LAT   2048
#define NFREQ 2074
#define KPAD  2112   // NFREQ padded up to a multiple of 64 (zero-filled)

typedef __bf16 bf16x8 __attribute__((ext_vector_type(8)));
typedef float  f32x4  __attribute__((ext_vector_type(4)));

__device__ __forceinline__ unsigned short f2bf(float f) {
    unsigned int u = __float_as_uint(f);
    u = (u + 0x7fffu + ((u >> 16) & 1u)) >> 16;
    return (unsigned short)u;
}

__device__ __forceinline__ void gload_lds16(const unsigned short* g, unsigned short* l) {
    __builtin_amdgcn_global_load_lds(
        (const __attribute__((address_space(1))) unsigned int*)g,
        (__attribute__((address_space(3))) unsigned int*)l,
        16, 0, 0);
}

// ---------------------------------------------------------------------------
// Ledger:
//  - gemm2 scan r0-r9: occupancy {17,33,70}% x schedules x conflicts {6M,0}
//    all land 50-57.5us. NOT latency-bound (r9: 70% occ, worse). NOT LDS-BW
//    (r2). NOT conflicts (r3: 0, neutral). Cost axis that tracks the data:
//    barriers-per-MFMA (r9: 1/4 worse; r0: 1/8 best; r2: 1/16 at half TLP
//    neutral). r10 (this): 1/32 at sound 3-stage -- BM=256 BN=128 BK=64,
//    8 waves of 64x64, 144KB LDS, 1 blk/CU, grid 16x16 full chip, vmcnt(6)
//    straddle. The 256^2 8-phase template would idle half the chip at N=2048.
//  - r5: software grid barrier = +80us OFF LIMITS; r1: coop launch illegal.
//  - r8 = BEST (191.6): gemm1 128x128/8w + x-cast overlap. gemm1/prep/scale
//    kept r8-exact this round; r9's bf16-out + nontemporal reverted (FETCH
//    rose; absmax doubled; no time win).
//  - Swizzle generalized for BK=64 (8 chunks/row): store logical 16B chunk c
//    of row r at physical c ^ (r&7); read addr uses same XOR; staging source
//    pre-swizzled. 16-lane read batch hits 8 chunks x 2 = 2-way = free.

// prep: 2112 transpose blocks (x-cast lives in gemm1's dispatch).
__global__ void prep_kernel(const float* __restrict__ W,
                            const float* __restrict__ cb,
                            unsigned short* __restrict__ WT,
                            unsigned short* __restrict__ cosT,
                            float* __restrict__ maxp) {
    __shared__ float t[64][65];
    const int bid = blockIdx.x;
    const int tid = threadIdx.x;
    if (bid == 0 && tid == 0) *maxp = -__builtin_inff();
    const float* in     = (bid < 1056) ? W  : cb;
    unsigned short* out = (bid < 1056) ? WT : cosT;
    int b2 = (bid < 1056) ? bid : bid - 1056;
    const int c0 = (b2 % 32) * 64;
    const int r0 = (b2 / 32) * 64;
    for (int i = tid; i < 1024; i += 256) {
        int rr = i >> 4;
        int c4 = (i & 15) * 4;
        int r  = r0 + rr;
        float4 v;
        if (r < NFREQ) v = *(const float4*)&in[(size_t)r * LAT + c0 + c4];
        else           v = make_float4(0.f, 0.f, 0.f, 0.f);
        t[rr][c4 + 0] = v.x; t[rr][c4 + 1] = v.y;
        t[rr][c4 + 2] = v.z; t[rr][c4 + 3] = v.w;
    }
    __syncthreads();
    for (int i = tid; i < 1024; i += 256) {
        int cc = i >> 4;
        int r4 = (i & 15) * 4;
        ushort4 o;
        o.x = f2bf(t[r4 + 0][cc]); o.y = f2bf(t[r4 + 1][cc]);
        o.z = f2bf(t[r4 + 2][cc]); o.w = f2bf(t[r4 + 3][cc]);
        *(ushort4*)&out[(size_t)(c0 + cc) * KPAD + r0 + r4] = o;
    }
}

// ---------------------------------------------------------------------------
// GEMM1 (r8 winner, unchanged): 128x128, 512 thr = 8 waves of 64x32, 3-stage
// BK=32, vmcnt(2) straddle, 2-chunk swizzle. dim3(16,32): y>=16 = x-cast.
template <int N, int K>
__global__ __launch_bounds__(512, 4)
void gemm1_kernel(const unsigned short* __restrict__ A,
                  const unsigned short* __restrict__ Bt,
                  unsigned short* __restrict__ C,
                  const float* __restrict__ x,
                  unsigned short* __restrict__ xb) {
    if (blockIdx.y >= 16) {
        const int cb  = (blockIdx.y - 16) * 16 + blockIdx.x;   // 0..255
        const int tid = threadIdx.x;
        const float4* x4 = (const float4*)x;
        uint4* o4 = (uint4*)xb;
        int i = cb * 512 + tid;
#pragma unroll
        for (int it = 0; it < 8; ++it, i += 131072) {
            float4 a = x4[2 * i];
            float4 b = x4[2 * i + 1];
            union { unsigned short us[8]; uint4 v; } p;
            p.us[0] = f2bf(a.x); p.us[1] = f2bf(a.y); p.us[2] = f2bf(a.z); p.us[3] = f2bf(a.w);
            p.us[4] = f2bf(b.x); p.us[5] = f2bf(b.y); p.us[6] = f2bf(b.z); p.us[7] = f2bf(b.w);
            o4[i] = p.v;
        }
        return;
    }

    __shared__ alignas(16) unsigned short As[3][128 * 32];
    __shared__ alignas(16) unsigned short Bs[3][128 * 32];

    const int tid  = threadIdx.x;
    const int wave = tid >> 6;
    const int lane = tid & 63;
    const int wm   = (wave >> 2) * 64;
    const int wn   = (wave & 3) * 32;
    const int quad = lane >> 4;
    const int l16  = lane & 15;

    const int mBase = blockIdx.y * 128;
    const int nBase = blockIdx.x * 128;

    const int srow = lane >> 2;
    const int sk   = (((lane & 3) ^ ((srow >> 1) & 3))) * 8;

    const unsigned short* Ab1 = A  + (size_t)(mBase + wave * 16 + srow) * K + sk;
    const unsigned short* Bb1 = Bt + (size_t)(nBase + wave * 16 + srow) * K + sk;
    const int coff = (wave * 16) * 32;

    const int pc = (quad ^ ((l16 >> 1) & 3)) * 8;

    constexpr int NIT = K / 32;
    gload_lds16(Ab1, &As[0][coff]);
    gload_lds16(Bb1, &Bs[0][coff]);

    f32x4 acc[4][2] = {};
    int bc = 0;
    for (int j = 0; j < NIT; ++j) {
        const int bn = (bc == 2) ? 0 : bc + 1;
        if (j + 1 < NIT) {
            const int k0 = (j + 1) * 32;
            gload_lds16(Ab1 + k0, &As[bn][coff]);
            gload_lds16(Bb1 + k0, &Bs[bn][coff]);
            asm volatile("s_waitcnt vmcnt(2)\n\ts_barrier" ::: "memory");
        } else {
            asm volatile("s_waitcnt vmcnt(0)\n\ts_barrier" ::: "memory");
        }
        bf16x8 af[4], bfr[2];
#pragma unroll
        for (int mi = 0; mi < 4; ++mi)
            af[mi] = *(const bf16x8*)&As[bc][(wm + mi * 16 + l16) * 32 + pc];
#pragma unroll
        for (int ni = 0; ni < 2; ++ni)
            bfr[ni] = *(const bf16x8*)&Bs[bc][(wn + ni * 16 + l16) * 32 + pc];
#pragma unroll
        for (int mi = 0; mi < 4; ++mi)
#pragma unroll
            for (int ni = 0; ni < 2; ++ni)
                acc[mi][ni] = __builtin_amdgcn_mfma_f32_16x16x32_bf16(
                    af[mi], bfr[ni], acc[mi][ni], 0, 0, 0);
        bc = bn;
    }

#pragma unroll
    for (int mi = 0; mi < 4; ++mi)
#pragma unroll
        for (int ni = 0; ni < 2; ++ni) {
            int col = nBase + wn + ni * 16 + l16;
#pragma unroll
            for (int r = 0; r < 4; ++r) {
                int row = mBase + wm + mi * 16 + quad * 4 + r;
                C[(size_t)row * N + col] = f2bf(acc[mi][ni][r]);
            }
        }
}

// ---------------------------------------------------------------------------
// GEMM2 (r10): BM=256 BN=128 BK=64. 512 thr = 8 waves of 64x64 (4m x 2n),
// acc[4][4]. 3-stage LDS (144KB, 1 blk/CU), r0-pattern: issue 6 DMAs (t+1)
// at start, vmcnt(6) straddle (full-iter load cover), ONE barrier per 32
// MFMA/wave (4x r0's amortization). 8-chunk swizzle (c ^ (row&7)).
// fp32 out + fused global max.
template <int N, int K>
__global__ __launch_bounds__(512, 2)
void gemm2_kernel(const unsigned short* __restrict__ A,
                  const unsigned short* __restrict__ Bt,
                  float* __restrict__ C,
                  float* __restrict__ maxp) {
    __shared__ alignas(16) unsigned short As[3][256 * 64];
    __shared__ alignas(16) unsigned short Bs[3][128 * 64];
    __shared__ float redbuf[8];

    const int tid  = threadIdx.x;
    const int wave = tid >> 6;          // 0..7
    const int lane = tid & 63;
    const int wm   = (wave >> 1) * 64;  // 0..192
    const int wn   = (wave & 1) * 64;   // 0..64
    const int quad = lane >> 4;
    const int l16  = lane & 15;

    const int mBase = blockIdx.y * 256;
    const int nBase = blockIdx.x * 128;

    // staging: wave w -> A rows [w*32,w*32+32) (4 DMAs), B rows [w*16,+16) (2)
    // DMA lane map: row = base + (lane>>3), chunk = lane&7;
    // source pre-swizzle: logical chunk = (lane&7) ^ (row&7), row&7 = lane>>3
    const int lrow = lane >> 3;                       // 0..7
    const int lchk = ((lane & 7) ^ lrow) * 8;         // elems
    const unsigned short* Ab = A  + (size_t)(mBase + wave * 32 + lrow) * K + lchk;
    const unsigned short* Bb = Bt + (size_t)(nBase + wave * 16 + lrow) * K + lchk;
    const int aoff = (wave * 32) * 64;                // elems into As[buf]
    const int boff = (wave * 16) * 64;

    // fragment read: row R, k-half kk, quad -> physical chunk (kk*4+quad)^(R&7)
    const int r7  = l16 & 7;
    const int pc0 = ((0 * 4 + quad) ^ r7) * 8;        // k-half 0
    const int pc1 = ((1 * 4 + quad) ^ r7) * 8;        // k-half 1

    constexpr int NIT = K / 64;   // 32
    // prologue: tile 0 (6 DMAs/wave)
#pragma unroll
    for (int d = 0; d < 4; ++d)
        gload_lds16(Ab + (size_t)(d * 8) * K, &As[0][aoff + d * 8 * 64]);
#pragma unroll
    for (int d = 0; d < 2; ++d)
        gload_lds16(Bb + (size_t)(d * 8) * K, &Bs[0][boff + d * 8 * 64]);

    f32x4 acc[4][4] = {};
    int bc = 0;
    for (int j = 0; j < NIT; ++j) {
        const int bn = (bc == 2) ? 0 : bc + 1;
        if (j + 1 < NIT) {
            const int k0 = (j + 1) * 64;
#pragma unroll
            for (int d = 0; d < 4; ++d)
                gload_lds16(Ab + (size_t)(d * 8) * K + k0, &As[bn][aoff + d * 8 * 64]);
#pragma unroll
            for (int d = 0; d < 2; ++d)
                gload_lds16(Bb + (size_t)(d * 8) * K + k0, &Bs[bn][boff + d * 8 * 64]);
            asm volatile("s_waitcnt vmcnt(6)\n\ts_barrier" ::: "memory");
        } else {
            asm volatile("s_waitcnt vmcnt(0)\n\ts_barrier" ::: "memory");
        }
        // ---- k-half 0 ----
        {
            bf16x8 af[4], bfr[4];
#pragma unroll
            for (int mi = 0; mi < 4; ++mi)
                af[mi] = *(const bf16x8*)&As[bc][(wm + mi * 16 + l16) * 64 + pc0];
#pragma unroll
            for (int ni = 0; ni < 4; ++ni)
                bfr[ni] = *(const bf16x8*)&Bs[bc][(wn + ni * 16 + l16) * 64 + pc0];
#pragma unroll
            for (int mi = 0; mi < 4; ++mi)
#pragma unroll
                for (int ni = 0; ni < 4; ++ni)
                    acc[mi][ni] = __builtin_amdgcn_mfma_f32_16x16x32_bf16(
                        af[mi], bfr[ni], acc[mi][ni], 0, 0, 0);
        }
        // ---- k-half 1 ----
        {
            bf16x8 af[4], bfr[4];
#pragma unroll
            for (int mi = 0; mi < 4; ++mi)
                af[mi] = *(const bf16x8*)&As[bc][(wm + mi * 16 + l16) * 64 + pc1];
#pragma unroll
            for (int ni = 0; ni < 4; ++ni)
                bfr[ni] = *(const bf16x8*)&Bs[bc][(wn + ni * 16 + l16) * 64 + pc1];
#pragma unroll
            for (int mi = 0; mi < 4; ++mi)
#pragma unroll
                for (int ni = 0; ni < 4; ++ni)
                    acc[mi][ni] = __builtin_amdgcn_mfma_f32_16x16x32_bf16(
                        af[mi], bfr[ni], acc[mi][ni], 0, 0, 0);
        }
        bc = bn;
    }

    // epilogue: fp32 store + block max + one atomic
    float vmax = -__builtin_inff();
#pragma unroll
    for (int mi = 0; mi < 4; ++mi)
#pragma unroll
        for (int ni = 0; ni < 4; ++ni) {
            int col = nBase + wn + ni * 16 + l16;
#pragma unroll
            for (int r = 0; r < 4; ++r) {
                int row = mBase + wm + mi * 16 + quad * 4 + r;
                float v = acc[mi][ni][r];
                C[(size_t)row * N + col] = v;
                vmax = fmaxf(vmax, v);
            }
        }
#pragma unroll
    for (int off = 32; off > 0; off >>= 1)
        vmax = fmaxf(vmax, __shfl_xor(vmax, off));
    if (lane == 0) redbuf[wave] = vmax;
    __syncthreads();
    if (tid == 0) {
        float m = redbuf[0];
#pragma unroll
        for (int w = 1; w < 8; ++w) m = fmaxf(m, redbuf[w]);
        if (m >= 0.0f) atomicMax((int*)maxp, __float_as_int(m));
        else           atomicMin((unsigned int*)maxp, __float_as_uint(m));
    }
}

// ---------------------------------------------------------------------------
__global__ void scale_kernel(float* __restrict__ out, const float* __restrict__ maxp) {
    int i = blockIdx.x * blockDim.x + threadIdx.x;
    float inv = 1.0f / (*maxp);
    float4* o4 = (float4*)out;
    float4 v = o4[i];
    v.x *= inv; v.y *= inv; v.z *= inv; v.w *= inv;
    o4[i] = v;
}

// ---------------------------------------------------------------------------
extern "C" void kernel_launch(void* const* d_in, const int* in_sizes, int n_in,
                              void* d_out, int out_size, void* d_ws, size_t ws_size,
                              hipStream_t stream) {
    const float* x  = (const float*)d_in[0];  // (4096, 2048)
    const float* W  = (const float*)d_in[1];  // (2074, 2048)
    const float* cb = (const float*)d_in[2];  // (2074, 2048)

    char* ws = (char*)d_ws;
    unsigned short* xb   = (unsigned short*)ws;                                   // [4096][2048] bf16
    unsigned short* WT   = (unsigned short*)(ws + (size_t)BATCH * LAT * 2);       // [2048][2112] bf16
    unsigned short* cosT = (unsigned short*)((char*)WT + (size_t)LAT * KPAD * 2);
    unsigned short* C1   = (unsigned short*)((char*)cosT + (size_t)LAT * KPAD * 2); // [2048][2048] bf16
    float*          maxp = (float*)((char*)C1 + (size_t)LAT * LAT * 2);
    float*          out  = (float*)d_out;

    // 1. prep: transpose+cast W and cos_basis (+init max)
    prep_kernel<<<2 * 1056, 256, 0, stream>>>(W, cb, WT, cosT, maxp);

    // 2. C1 = cosT x WT^T (128x128 tiles, 256 GEMM blocks) + 256 x-cast blocks
    gemm1_kernel<LAT, KPAD>
        <<<dim3(16, 32), 512, 0, stream>>>(cosT, WT, C1, x, xb);

    // 3. out[b][l2] = sum_l1 xb[b][l1] * C1[l2][l1]
    //    (256x128 tile, BK=64, 8 waves of 64x64, 1 blk/CU, grid 16x16)
    gemm2_kernel<LAT, LAT>
        <<<dim3(LAT / 128, BATCH / 256), 512, 0, stream>>>(xb, C1, out, maxp);

    // 4. out /= max
    scale_kernel<<<(out_size / 4) / 256, 256, 0, stream>>>(out, maxp);
}

// Round 11
// 180.845 us; speedup vs baseline: 1.0956x; 1.0050x over previous
//
#include <hip/hip_runtime.h>
#include <hip/hip_bf16.h>
#include <cstdint>

#define BATCH 4096
#define LAT   2048
#define NFREQ 2074
#define KPAD  2112   // NFREQ padded up to a multiple of 64 (zero-filled)

typedef __bf16 bf16x8 __attribute__((ext_vector_type(8)));
typedef float  f32x4  __attribute__((ext_vector_type(4)));

__device__ __forceinline__ unsigned short f2bf(float f) {
    unsigned int u = __float_as_uint(f);
    u = (u + 0x7fffu + ((u >> 16) & 1u)) >> 16;
    return (unsigned short)u;
}

__device__ __forceinline__ void gload_lds16(const unsigned short* g, unsigned short* l) {
    __builtin_amdgcn_global_load_lds(
        (const __attribute__((address_space(1))) unsigned int*)g,
        (__attribute__((address_space(3))) unsigned int*)l,
        16, 0, 0);
}

// ---------------------------------------------------------------------------
// Ledger:
//  - gemm2 axis found (r0/r9/r10): barriers-per-MFMA. 1/4=57us, 1/8=50,
//    1/32=42.2 (r10 WIN, prediction matched: MfmaUtil 33%, 818 TF). Residual
//    ~2100cyc/iter = LDS-pipe (176KB/iter). Bigger wave tiles would cut
//    reads/MFMA but every config collapses the grid (<256 blocks) or TLP
//    (4 waves/CU) at N=2048 -- r10 is the geometry optimum for this shape.
//  - r5: software grid barrier +80us OFF LIMITS; r1: coop launch illegal.
//  - r9 rider validated independently: bf16-unscaled out + converting scale
//    passes at absmax 0.0078 < 0.02. Re-applied here on the winning gemm2
//    (r11). NO nontemporal (r9: FETCH regression).
//  - Swizzles verified (conflicts 0): BK=32 rows: chunk c ^ ((r>>1)&3);
//    BK=64 rows: chunk c ^ (r&7). Both-sides (pre-swizzled gload source +
//    XOR on ds_read).

// prep: 2112 transpose blocks (x-cast lives in gemm1's dispatch).
__global__ void prep_kernel(const float* __restrict__ W,
                            const float* __restrict__ cb,
                            unsigned short* __restrict__ WT,
                            unsigned short* __restrict__ cosT,
                            float* __restrict__ maxp) {
    __shared__ float t[64][65];
    const int bid = blockIdx.x;
    const int tid = threadIdx.x;
    if (bid == 0 && tid == 0) *maxp = -__builtin_inff();
    const float* in     = (bid < 1056) ? W  : cb;
    unsigned short* out = (bid < 1056) ? WT : cosT;
    int b2 = (bid < 1056) ? bid : bid - 1056;
    const int c0 = (b2 % 32) * 64;
    const int r0 = (b2 / 32) * 64;
    for (int i = tid; i < 1024; i += 256) {
        int rr = i >> 4;
        int c4 = (i & 15) * 4;
        int r  = r0 + rr;
        float4 v;
        if (r < NFREQ) v = *(const float4*)&in[(size_t)r * LAT + c0 + c4];
        else           v = make_float4(0.f, 0.f, 0.f, 0.f);
        t[rr][c4 + 0] = v.x; t[rr][c4 + 1] = v.y;
        t[rr][c4 + 2] = v.z; t[rr][c4 + 3] = v.w;
    }
    __syncthreads();
    for (int i = tid; i < 1024; i += 256) {
        int cc = i >> 4;
        int r4 = (i & 15) * 4;
        ushort4 o;
        o.x = f2bf(t[r4 + 0][cc]); o.y = f2bf(t[r4 + 1][cc]);
        o.z = f2bf(t[r4 + 2][cc]); o.w = f2bf(t[r4 + 3][cc]);
        *(ushort4*)&out[(size_t)(c0 + cc) * KPAD + r0 + r4] = o;
    }
}

// ---------------------------------------------------------------------------
// GEMM1 (r8 winner, unchanged): 128x128, 512 thr = 8 waves of 64x32, 3-stage
// BK=32, vmcnt(2) straddle, 2-chunk swizzle. dim3(16,32): y>=16 = x-cast.
template <int N, int K>
__global__ __launch_bounds__(512, 4)
void gemm1_kernel(const unsigned short* __restrict__ A,
                  const unsigned short* __restrict__ Bt,
                  unsigned short* __restrict__ C,
                  const float* __restrict__ x,
                  unsigned short* __restrict__ xb) {
    if (blockIdx.y >= 16) {
        const int cb  = (blockIdx.y - 16) * 16 + blockIdx.x;   // 0..255
        const int tid = threadIdx.x;
        const float4* x4 = (const float4*)x;
        uint4* o4 = (uint4*)xb;
        int i = cb * 512 + tid;
#pragma unroll
        for (int it = 0; it < 8; ++it, i += 131072) {
            float4 a = x4[2 * i];
            float4 b = x4[2 * i + 1];
            union { unsigned short us[8]; uint4 v; } p;
            p.us[0] = f2bf(a.x); p.us[1] = f2bf(a.y); p.us[2] = f2bf(a.z); p.us[3] = f2bf(a.w);
            p.us[4] = f2bf(b.x); p.us[5] = f2bf(b.y); p.us[6] = f2bf(b.z); p.us[7] = f2bf(b.w);
            o4[i] = p.v;
        }
        return;
    }

    __shared__ alignas(16) unsigned short As[3][128 * 32];
    __shared__ alignas(16) unsigned short Bs[3][128 * 32];

    const int tid  = threadIdx.x;
    const int wave = tid >> 6;
    const int lane = tid & 63;
    const int wm   = (wave >> 2) * 64;
    const int wn   = (wave & 3) * 32;
    const int quad = lane >> 4;
    const int l16  = lane & 15;

    const int mBase = blockIdx.y * 128;
    const int nBase = blockIdx.x * 128;

    const int srow = lane >> 2;
    const int sk   = (((lane & 3) ^ ((srow >> 1) & 3))) * 8;

    const unsigned short* Ab1 = A  + (size_t)(mBase + wave * 16 + srow) * K + sk;
    const unsigned short* Bb1 = Bt + (size_t)(nBase + wave * 16 + srow) * K + sk;
    const int coff = (wave * 16) * 32;

    const int pc = (quad ^ ((l16 >> 1) & 3)) * 8;

    constexpr int NIT = K / 32;
    gload_lds16(Ab1, &As[0][coff]);
    gload_lds16(Bb1, &Bs[0][coff]);

    f32x4 acc[4][2] = {};
    int bc = 0;
    for (int j = 0; j < NIT; ++j) {
        const int bn = (bc == 2) ? 0 : bc + 1;
        if (j + 1 < NIT) {
            const int k0 = (j + 1) * 32;
            gload_lds16(Ab1 + k0, &As[bn][coff]);
            gload_lds16(Bb1 + k0, &Bs[bn][coff]);
            asm volatile("s_waitcnt vmcnt(2)\n\ts_barrier" ::: "memory");
        } else {
            asm volatile("s_waitcnt vmcnt(0)\n\ts_barrier" ::: "memory");
        }
        bf16x8 af[4], bfr[2];
#pragma unroll
        for (int mi = 0; mi < 4; ++mi)
            af[mi] = *(const bf16x8*)&As[bc][(wm + mi * 16 + l16) * 32 + pc];
#pragma unroll
        for (int ni = 0; ni < 2; ++ni)
            bfr[ni] = *(const bf16x8*)&Bs[bc][(wn + ni * 16 + l16) * 32 + pc];
#pragma unroll
        for (int mi = 0; mi < 4; ++mi)
#pragma unroll
            for (int ni = 0; ni < 2; ++ni)
                acc[mi][ni] = __builtin_amdgcn_mfma_f32_16x16x32_bf16(
                    af[mi], bfr[ni], acc[mi][ni], 0, 0, 0);
        bc = bn;
    }

#pragma unroll
    for (int mi = 0; mi < 4; ++mi)
#pragma unroll
        for (int ni = 0; ni < 2; ++ni) {
            int col = nBase + wn + ni * 16 + l16;
#pragma unroll
            for (int r = 0; r < 4; ++r) {
                int row = mBase + wm + mi * 16 + quad * 4 + r;
                C[(size_t)row * N + col] = f2bf(acc[mi][ni][r]);
            }
        }
}

// ---------------------------------------------------------------------------
// GEMM2 (r10 winner + r11 bf16-out): BM=256 BN=128 BK=64, 512 thr = 8 waves
// of 64x64 (4m x 2n), acc[4][4], 3-stage LDS 144KB, vmcnt(6) straddle, ONE
// barrier per 32 MFMA/wave. 8-chunk swizzle (c ^ (row&7)). Writes bf16
// UNSCALED (halves C-write; absmax 0.0078 validated r9) + fused global max.
template <int N, int K>
__global__ __launch_bounds__(512, 2)
void gemm2_kernel(const unsigned short* __restrict__ A,
                  const unsigned short* __restrict__ Bt,
                  unsigned short* __restrict__ Cb,
                  float* __restrict__ maxp) {
    __shared__ alignas(16) unsigned short As[3][256 * 64];
    __shared__ alignas(16) unsigned short Bs[3][128 * 64];
    __shared__ float redbuf[8];

    const int tid  = threadIdx.x;
    const int wave = tid >> 6;          // 0..7
    const int lane = tid & 63;
    const int wm   = (wave >> 1) * 64;  // 0..192
    const int wn   = (wave & 1) * 64;   // 0..64
    const int quad = lane >> 4;
    const int l16  = lane & 15;

    const int mBase = blockIdx.y * 256;
    const int nBase = blockIdx.x * 128;

    const int lrow = lane >> 3;                       // 0..7
    const int lchk = ((lane & 7) ^ lrow) * 8;         // pre-swizzled source chunk
    const unsigned short* Ab = A  + (size_t)(mBase + wave * 32 + lrow) * K + lchk;
    const unsigned short* Bb = Bt + (size_t)(nBase + wave * 16 + lrow) * K + lchk;
    const int aoff = (wave * 32) * 64;
    const int boff = (wave * 16) * 64;

    const int r7  = l16 & 7;
    const int pc0 = ((0 * 4 + quad) ^ r7) * 8;        // k-half 0
    const int pc1 = ((1 * 4 + quad) ^ r7) * 8;        // k-half 1

    constexpr int NIT = K / 64;   // 32
#pragma unroll
    for (int d = 0; d < 4; ++d)
        gload_lds16(Ab + (size_t)(d * 8) * K, &As[0][aoff + d * 8 * 64]);
#pragma unroll
    for (int d = 0; d < 2; ++d)
        gload_lds16(Bb + (size_t)(d * 8) * K, &Bs[0][boff + d * 8 * 64]);

    f32x4 acc[4][4] = {};
    int bc = 0;
    for (int j = 0; j < NIT; ++j) {
        const int bn = (bc == 2) ? 0 : bc + 1;
        if (j + 1 < NIT) {
            const int k0 = (j + 1) * 64;
#pragma unroll
            for (int d = 0; d < 4; ++d)
                gload_lds16(Ab + (size_t)(d * 8) * K + k0, &As[bn][aoff + d * 8 * 64]);
#pragma unroll
            for (int d = 0; d < 2; ++d)
                gload_lds16(Bb + (size_t)(d * 8) * K + k0, &Bs[bn][boff + d * 8 * 64]);
            asm volatile("s_waitcnt vmcnt(6)\n\ts_barrier" ::: "memory");
        } else {
            asm volatile("s_waitcnt vmcnt(0)\n\ts_barrier" ::: "memory");
        }
        {
            bf16x8 af[4], bfr[4];
#pragma unroll
            for (int mi = 0; mi < 4; ++mi)
                af[mi] = *(const bf16x8*)&As[bc][(wm + mi * 16 + l16) * 64 + pc0];
#pragma unroll
            for (int ni = 0; ni < 4; ++ni)
                bfr[ni] = *(const bf16x8*)&Bs[bc][(wn + ni * 16 + l16) * 64 + pc0];
#pragma unroll
            for (int mi = 0; mi < 4; ++mi)
#pragma unroll
                for (int ni = 0; ni < 4; ++ni)
                    acc[mi][ni] = __builtin_amdgcn_mfma_f32_16x16x32_bf16(
                        af[mi], bfr[ni], acc[mi][ni], 0, 0, 0);
        }
        {
            bf16x8 af[4], bfr[4];
#pragma unroll
            for (int mi = 0; mi < 4; ++mi)
                af[mi] = *(const bf16x8*)&As[bc][(wm + mi * 16 + l16) * 64 + pc1];
#pragma unroll
            for (int ni = 0; ni < 4; ++ni)
                bfr[ni] = *(const bf16x8*)&Bs[bc][(wn + ni * 16 + l16) * 64 + pc1];
#pragma unroll
            for (int mi = 0; mi < 4; ++mi)
#pragma unroll
                for (int ni = 0; ni < 4; ++ni)
                    acc[mi][ni] = __builtin_amdgcn_mfma_f32_16x16x32_bf16(
                        af[mi], bfr[ni], acc[mi][ni], 0, 0, 0);
        }
        bc = bn;
    }

    // epilogue: bf16 unscaled store + block max + one atomic
    float vmax = -__builtin_inff();
#pragma unroll
    for (int mi = 0; mi < 4; ++mi)
#pragma unroll
        for (int ni = 0; ni < 4; ++ni) {
            int col = nBase + wn + ni * 16 + l16;
#pragma unroll
            for (int r = 0; r < 4; ++r) {
                int row = mBase + wm + mi * 16 + quad * 4 + r;
                float v = acc[mi][ni][r];
                Cb[(size_t)row * N + col] = f2bf(v);
                vmax = fmaxf(vmax, v);
            }
        }
#pragma unroll
    for (int off = 32; off > 0; off >>= 1)
        vmax = fmaxf(vmax, __shfl_xor(vmax, off));
    if (lane == 0) redbuf[wave] = vmax;
    __syncthreads();
    if (tid == 0) {
        float m = redbuf[0];
#pragma unroll
        for (int w = 1; w < 8; ++w) m = fmaxf(m, redbuf[w]);
        if (m >= 0.0f) atomicMax((int*)maxp, __float_as_int(m));
        else           atomicMin((unsigned int*)maxp, __float_as_uint(m));
    }
}

// ---------------------------------------------------------------------------
// scale: bf16 unscaled -> scaled fp32. 8 bf16 in (16B), 8 fp32 out (32B).
__global__ void scale_kernel(const unsigned short* __restrict__ cbuf,
                             float* __restrict__ out,
                             const float* __restrict__ maxp) {
    int i = blockIdx.x * blockDim.x + threadIdx.x;
    float inv = 1.0f / (*maxp);
    union { uint4 v; unsigned short us[8]; } p;
    p.v = ((const uint4*)cbuf)[i];
    float4 o0, o1;
    o0.x = __uint_as_float((unsigned int)p.us[0] << 16) * inv;
    o0.y = __uint_as_float((unsigned int)p.us[1] << 16) * inv;
    o0.z = __uint_as_float((unsigned int)p.us[2] << 16) * inv;
    o0.w = __uint_as_float((unsigned int)p.us[3] << 16) * inv;
    o1.x = __uint_as_float((unsigned int)p.us[4] << 16) * inv;
    o1.y = __uint_as_float((unsigned int)p.us[5] << 16) * inv;
    o1.z = __uint_as_float((unsigned int)p.us[6] << 16) * inv;
    o1.w = __uint_as_float((unsigned int)p.us[7] << 16) * inv;
    ((float4*)out)[2 * i]     = o0;
    ((float4*)out)[2 * i + 1] = o1;
}

// ---------------------------------------------------------------------------
extern "C" void kernel_launch(void* const* d_in, const int* in_sizes, int n_in,
                              void* d_out, int out_size, void* d_ws, size_t ws_size,
                              hipStream_t stream) {
    const float* x  = (const float*)d_in[0];  // (4096, 2048)
    const float* W  = (const float*)d_in[1];  // (2074, 2048)
    const float* cb = (const float*)d_in[2];  // (2074, 2048)

    char* ws = (char*)d_ws;
    unsigned short* xb   = (unsigned short*)ws;                                   // [4096][2048] bf16
    unsigned short* WT   = (unsigned short*)(ws + (size_t)BATCH * LAT * 2);       // [2048][2112] bf16
    unsigned short* cosT = (unsigned short*)((char*)WT + (size_t)LAT * KPAD * 2);
    unsigned short* C1   = (unsigned short*)((char*)cosT + (size_t)LAT * KPAD * 2); // [2048][2048] bf16
    unsigned short* C2b  = (unsigned short*)((char*)C1 + (size_t)LAT * LAT * 2);  // [4096][2048] bf16
    float*          maxp = (float*)((char*)C2b + (size_t)BATCH * LAT * 2);
    float*          out  = (float*)d_out;

    // 1. prep: transpose+cast W and cos_basis (+init max)
    prep_kernel<<<2 * 1056, 256, 0, stream>>>(W, cb, WT, cosT, maxp);

    // 2. C1 = cosT x WT^T (128x128 tiles, 256 GEMM blocks) + 256 x-cast blocks
    gemm1_kernel<LAT, KPAD>
        <<<dim3(16, 32), 512, 0, stream>>>(cosT, WT, C1, x, xb);

    // 3. C2b[b][l2] = bf16( sum_l1 xb[b][l1] * C1[l2][l1] ) + global max
    //    (256x128 tile, BK=64, 8 waves of 64x64, 1 blk/CU, grid 16x16)
    gemm2_kernel<LAT, LAT>
        <<<dim3(LAT / 128, BATCH / 256), 512, 0, stream>>>(xb, C1, C2b, maxp);

    // 4. out = fp32(C2b) / max
    scale_kernel<<<(out_size / 8) / 256, 256, 0, stream>>>(C2b, out, maxp);
}